// Round 5
// baseline (14543.658 us; speedup 1.0000x reference)
//
#include <hip/hip_runtime.h>
#include <math.h>

#define B_ 64
#define T_ 512

// ---------------------------------------------------------------------------
// GEMM: C[M,N] = (A[M,K] * mask[row/T_, :]) @ W[K,N] + bias[N]
// fp32, 64x64 tile, TK=32, 256 threads, 4x4 microtile per thread.
// ---------------------------------------------------------------------------
__global__ __launch_bounds__(256) void gemm_mask_kernel(
    const float* __restrict__ A, const float* __restrict__ W,
    const float* __restrict__ bias, const float* __restrict__ mask,
    float* __restrict__ C, int M, int N, int K)
{
    const int TM = 64, TN = 64, TK = 32;
    __shared__ __align__(16) float As[TK][68];
    __shared__ __align__(16) float Bs[TK][68];

    const int tid = threadIdx.x;
    const int bn = blockIdx.x;
    const int bm = blockIdx.y;
    const int row0 = bm * TM;
    const int b = row0 / T_;

    const int ty = tid >> 4;
    const int tx = tid & 15;
    const int m0 = ty * 4;
    const int n0 = tx * 4;

    float acc[4][4];
#pragma unroll
    for (int i = 0; i < 4; i++)
#pragma unroll
        for (int j = 0; j < 4; j++) acc[i][j] = 0.f;

    for (int kk = 0; kk < K; kk += TK) {
        {
            const int r = tid >> 3;
            const int kq = (tid & 7) << 2;
            const float4 mv = *(const float4*)(mask + (size_t)b * K + kk + kq);
#pragma unroll
            for (int rr = 0; rr < 2; rr++) {
                const int r2 = r + rr * 32;
                const float4 av = *(const float4*)(A + (size_t)(row0 + r2) * K + kk + kq);
                As[kq + 0][r2] = av.x * mv.x;
                As[kq + 1][r2] = av.y * mv.y;
                As[kq + 2][r2] = av.z * mv.z;
                As[kq + 3][r2] = av.w * mv.w;
            }
        }
        {
            const int kr = tid >> 4;
            const int nq = (tid & 15) << 2;
#pragma unroll
            for (int rr = 0; rr < 2; rr++) {
                const int k2 = kr + rr * 16;
                const float4 bv = *(const float4*)(W + (size_t)(kk + k2) * N + bn * TN + nq);
                *(float4*)&Bs[k2][nq] = bv;
            }
        }
        __syncthreads();

#pragma unroll
        for (int k = 0; k < TK; k++) {
            const float4 av = *(const float4*)&As[k][m0];
            const float4 bv = *(const float4*)&Bs[k][n0];
            acc[0][0] += av.x * bv.x; acc[0][1] += av.x * bv.y; acc[0][2] += av.x * bv.z; acc[0][3] += av.x * bv.w;
            acc[1][0] += av.y * bv.x; acc[1][1] += av.y * bv.y; acc[1][2] += av.y * bv.z; acc[1][3] += av.y * bv.w;
            acc[2][0] += av.z * bv.x; acc[2][1] += av.z * bv.y; acc[2][2] += av.z * bv.z; acc[2][3] += av.z * bv.w;
            acc[3][0] += av.w * bv.x; acc[3][1] += av.w * bv.y; acc[3][2] += av.w * bv.z; acc[3][3] += av.w * bv.w;
        }
        __syncthreads();
    }

    const float4 bv = *(const float4*)(bias + bn * TN + n0);
#pragma unroll
    for (int i = 0; i < 4; i++) {
        float4 v;
        v.x = acc[i][0] + bv.x;
        v.y = acc[i][1] + bv.y;
        v.z = acc[i][2] + bv.z;
        v.w = acc[i][3] + bv.w;
        *(float4*)&C[(size_t)(row0 + m0 + i) * N + bn * TN + n0] = v;
    }
}

// ---------------------------------------------------------------------------
// LSTM recurrence v5: register-resident U at <=64 VGPRs/thread (the empirical
// no-spill limit: rounds 1/3/4 spilled at 128-reg demand, round 2's 64-reg
// staging stayed resident). 1024 threads/block, 4 blocks/batch, 256 blocks,
// 1 block/CU, all co-resident (VGPR hard-capped at 128 by launch_bounds).
// Thread (kq, cp): gate columns {2cp, 2cp+1} x k-range [kq*KH, (kq+1)*KH).
//   HN=256: CP=128, NKG=8,  KH=32 -> u2[32] = 64 VGPRs.
//   HN=128: CP=64,  NKG=16, KH=8  -> u2[8]  = 16 VGPRs.
// Per step: FMA vs LDS-broadcast h, NKG-way k-reduction via LDS, activations,
// cell update, 4-block h exchange via global hbuf + agent-scope flags
// (parity double-buffer, XCD-swizzled siblings). xz load pipelined one step.
// ---------------------------------------------------------------------------
__device__ __forceinline__ float fsig(float z) { return 1.f / (1.f + __expf(-z)); }
__device__ __forceinline__ float ftanh(float z) {
    const float e = __expf(2.f * z);
    return 1.f - 2.f / (e + 1.f);
}

template <int HN>
__global__ __launch_bounds__(1024) void lstm_rec_v5(
    const float* __restrict__ xz,   // [B, T, 4*HN]
    const float* __restrict__ U,    // [HN, 4*HN]
    float* __restrict__ hout,       // [B, T, HN] or nullptr
    float* __restrict__ out_last,   // [B, HN] or nullptr
    float* __restrict__ hbuf,       // [2][B_*HN] exchange buffer
    int* __restrict__ flags)        // [B_*4], zeroed before launch
{
    constexpr int GATES = 4 * HN;
    constexpr int COLS = HN;        // gate columns per block
    constexpr int CP = COLS / 2;    // column-pairs per block
    constexpr int NKG = 1024 / CP;  // k-groups
    constexpr int KH = HN / NKG;    // k per thread
    constexpr int HB = HN / 4;      // hidden units per block

    __shared__ __align__(16) float h_sh[HN];
    __shared__ __align__(16) float2 zpart[(NKG - 1) * CP];
    __shared__ __align__(16) float act_sh[COLS];

    const int tid = threadIdx.x;
    const int q = blockIdx.x >> 6;          // quarter 0..3
    const int b = blockIdx.x & 63;          // batch element (siblings share XCD)

    const int cp = tid % CP;                // column-pair
    const int kq = tid / CP;                // k-group (wave-uniform: CP % 64 == 0)
    const int c0 = 2 * cp;                  // local column
    const int group = c0 / HB;              // gate 0..3
    const int within = c0 % HB;
    const int gcol = group * HN + q * HB + within;
    const int kbase = kq * KH;

    // one-time: U fragment (KH k x 2 cols) into registers — 2*KH VGPRs
    float2 u2[KH];
#pragma unroll
    for (int j = 0; j < KH; ++j)
        u2[j] = *(const float2*)&U[(size_t)(kbase + j) * GATES + gcol];

    if (tid < HN) h_sh[tid] = 0.f;
    float cst = 0.f;

    const float* xzb = xz + (size_t)b * T_ * GATES + gcol;
    const int fbase = b * 4;
    const bool tanh_gate = (group == 2);

    float2 z0 = make_float2(0.f, 0.f);
    if (kq == 0) z0 = *(const float2*)xzb;   // step-0 xz
    __syncthreads();

#pragma unroll 1
    for (int t = 0; t < T_; ++t) {
        float2 za = make_float2(0.f, 0.f), zb = make_float2(0.f, 0.f);
#pragma unroll
        for (int j = 0; j < KH; j += 4) {
            const float4 h4 = *(const float4*)&h_sh[kbase + j];   // wave-uniform bcast
            za.x += h4.x * u2[j + 0].x; za.y += h4.x * u2[j + 0].y;
            zb.x += h4.y * u2[j + 1].x; zb.y += h4.y * u2[j + 1].y;
            za.x += h4.z * u2[j + 2].x; za.y += h4.z * u2[j + 2].y;
            zb.x += h4.w * u2[j + 3].x; zb.y += h4.w * u2[j + 3].y;
        }
        const float2 zsum = make_float2(za.x + zb.x, za.y + zb.y);
        if (kq != 0) zpart[(kq - 1) * CP + cp] = zsum;
        __syncthreads();

        if (kq == 0) {
            float zx = z0.x + zsum.x;
            float zy = z0.y + zsum.y;
#pragma unroll
            for (int r = 0; r < NKG - 1; ++r) {
                const float2 p = zpart[r * CP + cp];
                zx += p.x; zy += p.y;
            }
            float ax, ay;
            if (tanh_gate) { ax = ftanh(zx); ay = ftanh(zy); }
            else           { ax = fsig(zx);  ay = fsig(zy);  }
            *(float2*)&act_sh[c0] = make_float2(ax, ay);
        }
        __syncthreads();

        float hnew = 0.f;
        if (tid < HB) {
            const float ig = act_sh[tid];
            const float fg = act_sh[HB + tid];
            const float gg = act_sh[2 * HB + tid];
            const float og = act_sh[3 * HB + tid];
            cst = fg * cst + ig * gg;
            hnew = og * ftanh(cst);
            if (hout) hout[((size_t)b * T_ + t) * HN + q * HB + tid] = hnew;
            if (out_last && t == T_ - 1) out_last[(size_t)b * HN + q * HB + tid] = hnew;
        }

        // pipeline: issue next step's xz load now (covered by exchange+spin)
        if (kq == 0 && t + 1 < T_) z0 = *(const float2*)(xzb + (size_t)(t + 1) * GATES);

        if (t < T_ - 1) {
            const int s = t & 1;
            // publish own h slice (wave 0 only: HB <= 64)
            if (tid < HB)
                __hip_atomic_store(&hbuf[(size_t)s * B_ * HN + b * HN + q * HB + tid],
                                   hnew, __ATOMIC_RELAXED, __HIP_MEMORY_SCOPE_AGENT);
            if (tid == 0) {
                __threadfence();   // agent-scope fence covers wave 0's stores
                __hip_atomic_store(&flags[fbase + q], t + 1,
                                   __ATOMIC_RELEASE, __HIP_MEMORY_SCOPE_AGENT);
            }
            // spin on all 4 sibling flags (lanes 0..3 of wave 0)
            if (tid < 4) {
                while (__hip_atomic_load(&flags[fbase + tid],
                                         __ATOMIC_ACQUIRE, __HIP_MEMORY_SCOPE_AGENT) < t + 1)
                    __builtin_amdgcn_s_sleep(1);
            }
            __syncthreads();
            // pull full h into LDS (float4 coalesced)
            if (tid < HN / 4) {
                const float4 hv = *(const float4*)&hbuf[(size_t)s * B_ * HN + b * HN + 4 * tid];
                *(float4*)&h_sh[4 * tid] = hv;
            }
            __syncthreads();
        }
    }
}

// ---------------------------------------------------------------------------
// Launch
// ---------------------------------------------------------------------------
extern "C" void kernel_launch(void* const* d_in, const int* in_sizes, int n_in,
                              void* d_out, int out_size, void* d_ws, size_t ws_size,
                              hipStream_t stream)
{
    const float* x  = (const float*)d_in[0];
    const float* W0 = (const float*)d_in[1];
    const float* U0 = (const float*)d_in[2];
    const float* b0 = (const float*)d_in[3];
    const float* W1 = (const float*)d_in[4];
    const float* U1 = (const float*)d_in[5];
    const float* b1 = (const float*)d_in[6];
    const float* W2 = (const float*)d_in[7];
    const float* U2 = (const float*)d_in[8];
    const float* b2 = (const float*)d_in[9];
    const float* m0 = (const float*)d_in[10];
    const float* m1 = (const float*)d_in[11];
    const float* m2 = (const float*)d_in[12];
    float* out = (float*)d_out;

    // workspace layout (fp32):
    //   xz    : 134217728 B   (64*512*1024 floats, reused by all 3 layers)
    //   h0    :  33554432 B
    //   h1    :  33554432 B
    //   hbuf  :    131072 B   (2 x 64 x 256 floats, shared across layers)
    //   flags :      3072 B   (3 layers x 256 ints)
    char* ws = (char*)d_ws;
    float* xz   = (float*)ws;
    float* h0   = (float*)(ws + 134217728);
    float* h1   = (float*)(ws + 134217728 + 33554432);
    float* hbuf = (float*)(ws + 134217728 + 2 * 33554432);
    int*   flg  = (int*)  (ws + 134217728 + 2 * 33554432 + 131072);

    // flags must start at 0 every call (d_ws is poisoned 0xAA)
    hipMemsetAsync(flg, 0, 3 * 256 * sizeof(int), stream);

    const int M = B_ * T_;  // 32768

    // Layer 0
    gemm_mask_kernel<<<dim3(1024 / 64, M / 64), 256, 0, stream>>>(x, W0, b0, m0, xz, M, 1024, 128);
    lstm_rec_v5<256><<<256, 1024, 0, stream>>>(xz, U0, h0, nullptr, hbuf, flg);

    // Layer 1
    gemm_mask_kernel<<<dim3(1024 / 64, M / 64), 256, 0, stream>>>(h0, W1, b1, m1, xz, M, 1024, 256);
    lstm_rec_v5<256><<<256, 1024, 0, stream>>>(xz, U1, h1, nullptr, hbuf, flg + 256);

    // Layer 2 (H=128), emit last h only
    gemm_mask_kernel<<<dim3(512 / 64, M / 64), 256, 0, stream>>>(h1, W2, b2, m2, xz, M, 512, 256);
    lstm_rec_v5<128><<<256, 1024, 0, stream>>>(xz, U2, nullptr, out, hbuf, flg + 512);
}